// Round 15
// baseline (535.527 us; speedup 1.0000x reference)
//
#include <hip/hip_runtime.h>

// BiLSTM: T=16384 tokens = 128 segs x 128, D=1024, H=512, bidirectional.
// r15: FUSED producer/consumer cooperative kernel (256 blocks x 512 thr):
//  - blocks 0..127 (producers): 256x256 MFMA GEMM (r14 pipeline) computing
//    XP in POSITION-MAJOR layout (row' = pos*128 + seg), tiles processed in
//    urgency order (position-pairs 0,63,1,62,...). After each tile: stores
//    drained -> RELEASE fetch_add on flag[postile] (wbl2 publish, r3-proven).
//  - blocks 128..255 (consumers): r10 persistent recurrence (16 chains x 64
//    units, W_hh in regs, group=8, LLC h-exchange, r4 barrier), with XP
//    prefetch gated on flag[postile]==16 (relaxed-agent poll, r4-proven).
// cast_x / pack_w / wr_bounds unchanged.

typedef __attribute__((ext_vector_type(8))) short bf16x8;
typedef __attribute__((ext_vector_type(4))) float f32x4;

__device__ __forceinline__ unsigned short f2bf(float f) {
  unsigned int x = __builtin_bit_cast(unsigned int, f);
  x += 0x7fffu + ((x >> 16) & 1u);
  return (unsigned short)(x >> 16);
}
__device__ __forceinline__ float bf2f(unsigned short u) {
  unsigned int x = ((unsigned int)u) << 16;
  return __builtin_bit_cast(float, x);
}
__device__ __forceinline__ float sigm(float x) { return 1.f / (1.f + __expf(-x)); }
__device__ __forceinline__ float tanhfast(float x) {
  float e = __expf(2.f * x);
  return 1.f - 2.f / (e + 1.f);
}

__device__ __forceinline__ void gl_lds16(const void* g, void* l) {
  __builtin_amdgcn_global_load_lds((const __attribute__((address_space(1))) unsigned int*)g,
                                   (__attribute__((address_space(3))) unsigned int*)l, 16, 0, 0);
}
// LLC-coherent variant: aux = SC0|SC1 -> bypass L1/L2, read from LLC.
__device__ __forceinline__ void gl_lds16_llc(const void* g, void* l) {
  __builtin_amdgcn_global_load_lds((const __attribute__((address_space(1))) unsigned int*)g,
                                   (__attribute__((address_space(3))) unsigned int*)l, 16, 0, 17);
}

// ---------------- cast X to bf16 ----------------
__global__ __launch_bounds__(256) void cast_x(const float* __restrict__ X,
                                              unsigned short* __restrict__ Xb) {
  const int i = blockIdx.x * 256 + threadIdx.x;
  const float4 v = ((const float4*)X)[i];
  uint2 o;
  o.x = (unsigned int)f2bf(v.x) | ((unsigned int)f2bf(v.y) << 16);
  o.y = (unsigned int)f2bf(v.z) | ((unsigned int)f2bf(v.w) << 16);
  ((uint2*)Xb)[i] = o;
}

// ---------------- pack W_ih (concat dirs) to bf16 + bias ----------------
__global__ __launch_bounds__(256) void pack_w(const float* __restrict__ Wif,
                                              const float* __restrict__ bf_,
                                              const float* __restrict__ Wib,
                                              const float* __restrict__ bb_,
                                              unsigned short* __restrict__ Wc,
                                              float* __restrict__ biasp) {
  const int pr = blockIdx.x;  // 0..4095
  const int d = pr >> 11, r = pr & 2047;
  const float* src = (d ? Wib : Wif) + (size_t)r * 1024;
  const int t = threadIdx.x;
  const float4 v = ((const float4*)src)[t];
  uint2 o;
  o.x = (unsigned int)f2bf(v.x) | ((unsigned int)f2bf(v.y) << 16);
  o.y = (unsigned int)f2bf(v.z) | ((unsigned int)f2bf(v.w) << 16);
  ((uint2*)(Wc + (size_t)pr * 1024))[t] = o;
  if (t == 0) biasp[pr] = (d ? bb_ : bf_)[r];
}

// ---------------- fused producer/consumer ----------------
__global__ __launch_bounds__(512, 1) void fused_bilstm(
    const unsigned short* __restrict__ A,      // Xb [16384][1024] bf16 (token-major)
    const unsigned short* __restrict__ B,      // Wc [4096][1024] bf16
    const float* __restrict__ bias,            // [4096]
    unsigned short* __restrict__ XPb,          // [16384][4096] bf16, POS-MAJOR rows
    const float* __restrict__ Whf, const float* __restrict__ Whb,
    unsigned short* __restrict__ hb0, unsigned short* __restrict__ hb1,
    float* __restrict__ out, unsigned int* __restrict__ ctr,
    unsigned int* __restrict__ flags) {
  __shared__ unsigned short SMEM[65536];  // 128 KB (producer); consumer uses 18 KB
  const int tid = threadIdx.x;
  const int bidg = blockIdx.x;
  const int lane = tid & 63;

  if (bidg < 128) {
    // ================= PRODUCER (r14 gemm, pos-major rows, 8 tiles) =================
    const int pid = bidg;
    const int wid = tid >> 6;
    const int wm = wid >> 2;  // 0..1
    const int wn = wid & 3;   // 0..3
    const int p15 = lane & 15;
    const int kq = lane >> 4;

    int srow[2], scol[2];
#pragma unroll
    for (int j = 0; j < 2; ++j) {
      const int o = (j * 512 + tid) * 16;
      srow[j] = o >> 7;
      scol[j] = (o & 127) ^ ((srow[j] & 7) << 4);  // inverse swizzle
    }

    for (int it = 0; it < 8; ++it) {
      const int L = pid + it * 128;                       // 0..1023 urgency index
      const int k = L >> 4;                               // rank 0..63
      const int nt = L & 15;                              // N-tile
      const int pm = (k & 1) ? (63 - (k >> 1)) : (k >> 1);  // postile (M-tile)
      const long brow = (long)pm * 256;  // pos-major row base
      const long bcol = (long)nt * 256;

      f32x4 acc[8][4];
      const f32x4 z = {0.f, 0.f, 0.f, 0.f};
#pragma unroll
      for (int m = 0; m < 8; ++m)
#pragma unroll
        for (int n = 0; n < 4; ++n) acc[m][n] = z;

#define STAGE_HALF(t, h, buf)                                                        \
  do {                                                                               \
    char* dA_ = (char*)(SMEM + ((buf)*2 + (h)) * 8192);                              \
    char* dB_ = (char*)(SMEM + 32768 + ((buf)*2 + (h)) * 8192);                      \
    _Pragma("unroll") for (int j_ = 0; j_ < 2; ++j_) {                               \
      const int o_ = (j_ * 512 + tid) * 16;                                          \
      const int rA_ = (int)brow + (h)*128 + srow[j_];                                \
      const long tokA_ = ((long)(rA_ & 127) << 7) + (rA_ >> 7);                      \
      gl_lds16((const char*)A + tokA_ * 2048 + (t)*128 + scol[j_], dA_ + o_);        \
      const long rB_ = bcol + (h)*128 + srow[j_];                                    \
      gl_lds16((const char*)B + rB_ * 2048 + (t)*128 + scol[j_], dB_ + o_);          \
    }                                                                                \
  } while (0)

      STAGE_HALF(0, 0, 0);
      STAGE_HALF(0, 1, 0);

      for (int t = 0; t < 16; ++t) {
        const int cur = t & 1, nxt = cur ^ 1;
        const bool doStage = (t + 1 < 16);
        const unsigned short* Acur = SMEM + (cur * 2 + wm) * 8192;
        const unsigned short* Bcur = SMEM + 32768 + (cur * 2 + (wn >> 1)) * 8192;
#pragma unroll
        for (int p = 0; p < 4; ++p) {
          if (p < 2 && doStage) STAGE_HALF(t + 1, p, nxt);
          if (p == 0) {
            if (doStage)
              asm volatile("s_waitcnt vmcnt(4)" ::: "memory");
            else
              asm volatile("s_waitcnt vmcnt(0)" ::: "memory");
          }
          __builtin_amdgcn_s_barrier();
          bf16x8 af[2][2], bf[4][2];
#pragma unroll
          for (int mm = 0; mm < 2; ++mm) {
            const int ar = (2 * p + mm) * 16 + p15;
            const char* abase = (const char*)Acur + ar * 128;
            const int asw = (ar & 7) << 4;
#pragma unroll
            for (int kk = 0; kk < 2; ++kk)
              af[mm][kk] = *(const bf16x8*)(abase + ((kk * 64 + kq * 16) ^ asw));
          }
#pragma unroll
          for (int n = 0; n < 4; ++n) {
            const int br = (wn & 1) * 64 + n * 16 + p15;
            const char* bbase = (const char*)Bcur + br * 128;
            const int bsw = (br & 7) << 4;
#pragma unroll
            for (int kk = 0; kk < 2; ++kk)
              bf[n][kk] = *(const bf16x8*)(bbase + ((kk * 64 + kq * 16) ^ bsw));
          }
          __builtin_amdgcn_s_setprio(1);
#pragma unroll
          for (int kk = 0; kk < 2; ++kk)
#pragma unroll
            for (int mm = 0; mm < 2; ++mm)
#pragma unroll
              for (int n = 0; n < 4; ++n)
                acc[2 * p + mm][n] = __builtin_amdgcn_mfma_f32_16x16x32_bf16(
                    af[mm][kk], bf[n][kk], acc[2 * p + mm][n], 0, 0, 0);
          __builtin_amdgcn_s_setprio(0);
          __builtin_amdgcn_s_barrier();
        }
      }
#undef STAGE_HALF

      __syncthreads();  // all ds reads done before SMEM reuse
      // epilogue: acc -> SMEM (bf16 + bias), then coalesced 16B stores
      const int crow0 = wm * 128 + kq * 4;
      const int ccol0 = wn * 64 + p15;
#pragma unroll
      for (int m = 0; m < 8; ++m) {
#pragma unroll
        for (int n = 0; n < 4; ++n) {
          const int col = ccol0 + n * 16;
          const float bsv = bias[bcol + col];
#pragma unroll
          for (int r = 0; r < 4; ++r)
            SMEM[(crow0 + m * 16 + r) * 256 + col] = f2bf(acc[m][n][r] + bsv);
        }
      }
      __syncthreads();
#pragma unroll
      for (int i = 0; i < 16; ++i) {
        const int id = i * 512 + tid;
        const int row = id >> 5;
        const int c = id & 31;
        *(float4*)(XPb + (brow + row) * 4096 + bcol + c * 8) =
            *(const float4*)(SMEM + row * 256 + c * 8);
      }
      __syncthreads();  // per-wave vmcnt(0): all C stores drained to L2
      if (tid == 0) {
        // RELEASE publish (wbl2 -> LLC), then count this tile for postile pm
        __hip_atomic_fetch_add(flags + pm * 32, 1u, __ATOMIC_RELEASE,
                               __HIP_MEMORY_SCOPE_AGENT);
      }
      __syncthreads();  // flag ordered before next tile's SMEM overwrite
    }
  } else {
    // ================= CONSUMER (r10 persist + pos-major XP + gating) =================
    unsigned short* A_s = SMEM;                              // 16 KB
    unsigned short(*Hrep)[64] = (unsigned short(*)[64])(SMEM + 8192);  // 2 KB

    const int cid = bidg - 128;
    const int ut = cid >> 4;   // 0..7: 64-unit tile; member index in group
    const int grp = cid & 15;  // group id
    const int dir = grp >> 3;
    const int cs = grp & 7;
    const int w = tid >> 6;  // 0..7
    const int p = lane & 15;
    const int kq8 = lane >> 4;
    const int hi = p >> 3;
    const int u_l = w * 8 + (p & 7);  // 0..63
    const int u_g = ut * 64 + u_l;    // 0..511
    unsigned int* const myctr = ctr + grp * 32;

    // W_hh slice -> registers (r10-proven layout)
    bf16x8 wreg[2][16];
    {
      const float* Wh = dir ? Whb : Whf;
#pragma unroll
      for (int f = 0; f < 2; ++f) {
        const int g = f * 2 + hi;
        const float* wrow = Wh + (size_t)(g * 512 + u_g) * 512 + kq8 * 8;
#pragma unroll
        for (int kk = 0; kk < 16; ++kk) {
          const float4 v0 = *(const float4*)(wrow + kk * 32);
          const float4 v1 = *(const float4*)(wrow + kk * 32 + 4);
          bf16x8 t;
          t[0] = (short)f2bf(v0.x); t[1] = (short)f2bf(v0.y);
          t[2] = (short)f2bf(v0.z); t[3] = (short)f2bf(v0.w);
          t[4] = (short)f2bf(v1.x); t[5] = (short)f2bf(v1.y);
          t[6] = (short)f2bf(v1.z); t[7] = (short)f2bf(v1.w);
          wreg[f][kk] = t;
        }
      }
    }

    float c_reg[2] = {0.f, 0.f};
    const size_t tileoff = (size_t)grp * 16384;
    const int cl0 = kq8 * 4 + 2 * hi;

    // gate + XP prefetch for tau=0 (pos-major rows: tok' = tcol*128 + seg)
    unsigned short xpr[2][4];
    {
      const int tcol0 = dir ? 127 : 0;
      if (tid == 0) {
        while (__hip_atomic_load(flags + (tcol0 >> 1) * 32, __ATOMIC_RELAXED,
                                 __HIP_MEMORY_SCOPE_AGENT) < 16u)
          __builtin_amdgcn_s_sleep(1);
      }
      __syncthreads();
#pragma unroll
      for (int j = 0; j < 2; ++j) {
        const int seg = cs * 16 + cl0 + j;
        const size_t tokp = (size_t)tcol0 * 128 + seg;
        const unsigned short* xp = XPb + tokp * 4096 + dir * 2048 + u_g;
#pragma unroll
        for (int g = 0; g < 4; ++g) xpr[j][g] = xp[g * 512];
      }
    }

    float phv[2];
    size_t pofs[2] = {0, 0};

    for (int tau = 0; tau < 128; ++tau) {
      const unsigned short* hc = (tau & 1) ? hb1 : hb0;
      unsigned short* hn = (tau & 1) ? hb0 : hb1;
      const int tcol = dir ? (127 - tau) : tau;

      // stage h tile from LLC (pre-swizzled; linear 16 KB copy)
      {
        const char* srcb = (const char*)hc + tileoff;
        char* dstb = (char*)A_s;
#pragma unroll
        for (int j = 0; j < 2; ++j) {
          const int o = (j * 512 + tid) * 16;
          gl_lds16_llc(srcb + o, dstb + o);
        }
      }
      // deferred out-stores for previous step
      if (tau > 0) {
        out[pofs[0]] = phv[0];
        out[pofs[1]] = phv[1];
      }
      // gate next step's XP postile while the stage is in flight
      if (tau < 127 && tid == 0) {
        const int tcolN = dir ? (126 - tau) : (tau + 1);
        while (__hip_atomic_load(flags + (tcolN >> 1) * 32, __ATOMIC_RELAXED,
                                 __HIP_MEMORY_SCOPE_AGENT) < 16u)
          __builtin_amdgcn_s_sleep(1);
      }
      __syncthreads();  // A_s ready + gate passed

      // XP prefetch for tau+1
      unsigned short xprN[2][4];
      if (tau < 127) {
        const int tcolN = dir ? (126 - tau) : (tau + 1);
#pragma unroll
        for (int j = 0; j < 2; ++j) {
          const int seg = cs * 16 + cl0 + j;
          const size_t tokp = (size_t)tcolN * 128 + seg;
          const unsigned short* xp = XPb + tokp * 4096 + dir * 2048 + u_g;
#pragma unroll
          for (int g = 0; g < 4; ++g) xprN[j][g] = xp[g * 512];
        }
      }

      // MFMA full K=512 (r10-proven)
      f32x4 accp[2][2];
      const f32x4 z = {0.f, 0.f, 0.f, 0.f};
      accp[0][0] = z; accp[0][1] = z; accp[1][0] = z; accp[1][1] = z;
      {
        const char* abase = (const char*)A_s + p * 1024;
        const int asw = (p & 7) << 4;
#pragma unroll
        for (int kk = 0; kk < 16; ++kk) {
          const int kb = kk * 64 + kq8 * 16;
          const bf16x8 af = *(const bf16x8*)(abase + (kb ^ asw));
          accp[0][kk & 1] =
              __builtin_amdgcn_mfma_f32_16x16x32_bf16(af, wreg[0][kk], accp[0][kk & 1], 0, 0, 0);
          accp[1][kk & 1] =
              __builtin_amdgcn_mfma_f32_16x16x32_bf16(af, wreg[1][kk], accp[1][kk & 1], 0, 0, 0);
        }
      }
      f32x4 acc0, acc1;
#pragma unroll
      for (int r = 0; r < 4; ++r) {
        acc0[r] = accp[0][0][r] + accp[0][1][r];
        acc1[r] = accp[1][0][r] + accp[1][1][r];
      }

      // gate combine (r5/r10 mapping)
      float hvr[2];
      {
        const float s0 = hi ? acc0[0] : acc0[2];
        const float s1 = hi ? acc0[1] : acc0[3];
        const float s2 = hi ? acc1[0] : acc1[2];
        const float s3 = hi ? acc1[1] : acc1[3];
        const float e0 = __shfl_xor(s0, 8);
        const float e1 = __shfl_xor(s1, 8);
        const float e2 = __shfl_xor(s2, 8);
        const float e3 = __shfl_xor(s3, 8);
        const float a0 = hi ? acc0[2] : acc0[0];
        const float a1 = hi ? acc0[3] : acc0[1];
        const float b0 = hi ? acc1[2] : acc1[0];
        const float b1 = hi ? acc1[3] : acc1[1];
        const float gi[2] = {hi ? e0 : a0, hi ? e1 : a1};
        const float gf[2] = {hi ? a0 : e0, hi ? a1 : e1};
        const float gg[2] = {hi ? e2 : b0, hi ? e3 : b1};
        const float go[2] = {hi ? b0 : e2, hi ? b1 : e3};
#pragma unroll
        for (int j = 0; j < 2; ++j) {
          const int cl = cl0 + j;
          const float pi = gi[j] + bf2f(xpr[j][0]);
          const float pf = gf[j] + bf2f(xpr[j][1]);
          const float pg = gg[j] + bf2f(xpr[j][2]);
          const float po = go[j] + bf2f(xpr[j][3]);
          float cv = sigm(pf) * c_reg[j] + sigm(pi) * tanhfast(pg);
          c_reg[j] = cv;
          hvr[j] = sigm(po) * tanhfast(cv);
          Hrep[cl][u_l] = f2bf(hvr[j]);
          const int seg = cs * 16 + cl;
          const size_t tok = (size_t)seg * 128 + tcol;  // out stays token-major
          pofs[j] = tok * 1024 + dir * 512 + u_g;
          phv[j] = hvr[j];
        }
      }
#pragma unroll
      for (int j = 0; j < 2; ++j)
#pragma unroll
        for (int g = 0; g < 4; ++g) xpr[j][g] = xprN[j][g];

      __syncthreads();  // Hrep complete

      // packed 8B LLC-coherent h stores (swizzled dest)
      if (tid < 256) {
        const int cl = tid >> 4, q = tid & 15;
        const unsigned long long v = *(const unsigned long long*)&Hrep[cl][q * 4];
        char* dst = (char*)hn + tileoff + cl * 1024 + ((ut * 128 + q * 8) ^ ((cl & 7) << 4));
        __hip_atomic_store((unsigned long long*)dst, v, __ATOMIC_RELAXED,
                           __HIP_MEMORY_SCOPE_AGENT);
      }

      // per-group barrier (fence-free, r4 protocol; 8 members)
      __syncthreads();  // drains vmcnt(0): sc1 stores at LLC
      if (tid == 0) {
        const unsigned old =
            __hip_atomic_fetch_add(myctr, 1u, __ATOMIC_RELAXED, __HIP_MEMORY_SCOPE_AGENT);
        const unsigned tgt = (unsigned)(tau + 1) * 8u;
        if (old + 1u != tgt) {
          while (__hip_atomic_load(myctr, __ATOMIC_RELAXED, __HIP_MEMORY_SCOPE_AGENT) < tgt)
            __builtin_amdgcn_s_sleep(1);
        }
      }
      __syncthreads();
    }
    out[pofs[0]] = phv[0];
    out[pofs[1]] = phv[1];
  }
}

// ---------------- boundaries passthrough ----------------
__global__ void wr_bounds(const int* __restrict__ b, float* __restrict__ o) {
  const int i = threadIdx.x;
  if (i < 129) o[i] = (float)b[i];
}

extern "C" void kernel_launch(void* const* d_in, const int* in_sizes, int n_in,
                              void* d_out, int out_size, void* d_ws, size_t ws_size,
                              hipStream_t stream) {
  const float* X = (const float*)d_in[0];
  const int* bnd = (const int*)d_in[1];
  const float* Wif = (const float*)d_in[2];
  const float* Whf = (const float*)d_in[3];
  const float* bf_ = (const float*)d_in[4];
  const float* Wib = (const float*)d_in[5];
  const float* Whb = (const float*)d_in[6];
  const float* bb_ = (const float*)d_in[7];
  float* out = (float*)d_out;

  wr_bounds<<<1, 256, 0, stream>>>(bnd, out + 16777216);

  char* ws = (char*)d_ws;
  const size_t NEED = 176711680ULL;
  if (ws_size < NEED) return;

  unsigned short* XPb = (unsigned short*)(ws + 0);          // 128 MB (pos-major)
  unsigned short* Xb = (unsigned short*)(ws + 134217728);   // 32 MB
  unsigned short* Wc = (unsigned short*)(ws + 167772160);   // 8 MB
  float* biasp = (float*)(ws + 176160768);                  // 16 KB
  unsigned short* hb0 = (unsigned short*)(ws + 176177152);  // 256 KB
  unsigned short* hb1 = (unsigned short*)(ws + 176439296);  // 256 KB
  unsigned int* ctrp = (unsigned int*)(ws + 176701440);     // 2 KB (16 x 128B)
  unsigned int* flagp = (unsigned int*)(ws + 176703488);    // 8 KB (64 x 128B)

  cast_x<<<16384, 256, 0, stream>>>(X, Xb);
  pack_w<<<4096, 256, 0, stream>>>(Wif, bf_, Wib, bb_, Wc, biasp);

  hipMemsetAsync(hb0, 0, 262144, stream);
  hipMemsetAsync(ctrp, 0, 2048, stream);
  hipMemsetAsync(flagp, 0, 8192, stream);

  {
    const unsigned short* a = Xb;
    const unsigned short* b = Wc;
    const float* bp = biasp;
    unsigned short* xpb = XPb;
    const float* whf = Whf;
    const float* whb = Whb;
    unsigned short* h0 = hb0;
    unsigned short* h1 = hb1;
    float* op = out;
    unsigned int* cp = ctrp;
    unsigned int* fp = flagp;
    void* args[] = {&a, &b, &bp, &xpb, &whf, &whb, &h0, &h1, &op, &cp, &fp};
    hipError_t e = hipLaunchCooperativeKernel((const void*)fused_bilstm, dim3(256), dim3(512),
                                              args, 0, stream);
    if (e != hipSuccess) {
      // fallback: plain launch; 256 blocks @ 1 block/CU co-reside
      fused_bilstm<<<256, 512, 0, stream>>>(Xb, Wc, biasp, XPb, Whf, Whb, hb0, hb1, out, ctrp,
                                            flagp);
    }
  }
}

// Round 16
// 487.039 us; speedup vs baseline: 1.0996x; 1.0996x over previous
//
#include <hip/hip_runtime.h>

// BiLSTM: T=16384 tokens = 128 segs x 128, D=1024, H=512, bidirectional.
// FINAL (r16 = r12-exact, best measured 489.5us):
//  1) cast X -> bf16; pack W_ih_f|W_ih_b -> bf16 [4096][1024]; bias concat.
//  2) MFMA GEMM: 256x256 tile, BK=64, 8 waves, 128KB LDS double-buffer,
//     4-phase/tile interleave (stage-issue || ds_read -> s_barrier -> setprio
//     -> 16 MFMA -> s_barrier), T2 XOR-swizzle both-sides, LDS-repacked
//     coalesced epilogue. (~168us, ~820 TF)
//  3) Persistent recurrence (cooperative, 256 blocks, r8): W_hh in registers
//     (wreg[2][16] = 128 VGPR/lane), full-K waves, LLC-coherent (sc0|sc1)
//     h exchange, fence-free relaxed-counter barrier, deferred out-stores,
//     XP prefetch pipeline. (~296us = 2.31us/step communication floor)
//  4) boundaries as floats to d_out tail.

typedef __attribute__((ext_vector_type(8))) short bf16x8;
typedef __attribute__((ext_vector_type(4))) float f32x4;

__device__ __forceinline__ unsigned short f2bf(float f) {
  unsigned int x = __builtin_bit_cast(unsigned int, f);
  x += 0x7fffu + ((x >> 16) & 1u);
  return (unsigned short)(x >> 16);
}
__device__ __forceinline__ float bf2f(unsigned short u) {
  unsigned int x = ((unsigned int)u) << 16;
  return __builtin_bit_cast(float, x);
}
__device__ __forceinline__ float sigm(float x) { return 1.f / (1.f + __expf(-x)); }
__device__ __forceinline__ float tanhfast(float x) {
  float e = __expf(2.f * x);
  return 1.f - 2.f / (e + 1.f);
}

__device__ __forceinline__ void gl_lds16(const void* g, void* l) {
  __builtin_amdgcn_global_load_lds((const __attribute__((address_space(1))) unsigned int*)g,
                                   (__attribute__((address_space(3))) unsigned int*)l, 16, 0, 0);
}
// LLC-coherent variant: aux = SC0|SC1 -> bypass L1/L2, read from LLC.
__device__ __forceinline__ void gl_lds16_llc(const void* g, void* l) {
  __builtin_amdgcn_global_load_lds((const __attribute__((address_space(1))) unsigned int*)g,
                                   (__attribute__((address_space(3))) unsigned int*)l, 16, 0, 17);
}

// ---------------- cast X to bf16 ----------------
__global__ __launch_bounds__(256) void cast_x(const float* __restrict__ X,
                                              unsigned short* __restrict__ Xb) {
  const int i = blockIdx.x * 256 + threadIdx.x;
  const float4 v = ((const float4*)X)[i];
  uint2 o;
  o.x = (unsigned int)f2bf(v.x) | ((unsigned int)f2bf(v.y) << 16);
  o.y = (unsigned int)f2bf(v.z) | ((unsigned int)f2bf(v.w) << 16);
  ((uint2*)Xb)[i] = o;
}

// ---------------- pack W_ih (concat dirs) to bf16 + bias ----------------
__global__ __launch_bounds__(256) void pack_w(const float* __restrict__ Wif,
                                              const float* __restrict__ bf_,
                                              const float* __restrict__ Wib,
                                              const float* __restrict__ bb_,
                                              unsigned short* __restrict__ Wc,
                                              float* __restrict__ biasp) {
  const int pr = blockIdx.x;  // 0..4095
  const int d = pr >> 11, r = pr & 2047;
  const float* src = (d ? Wib : Wif) + (size_t)r * 1024;
  const int t = threadIdx.x;
  const float4 v = ((const float4*)src)[t];
  uint2 o;
  o.x = (unsigned int)f2bf(v.x) | ((unsigned int)f2bf(v.y) << 16);
  o.y = (unsigned int)f2bf(v.z) | ((unsigned int)f2bf(v.w) << 16);
  ((uint2*)(Wc + (size_t)pr * 1024))[t] = o;
  if (t == 0) biasp[pr] = (d ? bb_ : bf_)[r];
}

// ---------------- MFMA GEMM: XP = Xb @ Wc^T + bias (256^2 8-phase) ----------------
// A [16384][1024], B [4096][1024] (B^T layout), C [16384][4096], all bf16.
// 512 thr = 8 waves: wm=wid>>2 (2 M-halves), wn=wid&3 (4 N-quarters).
// Wave output 128x64 = 8x4 frags of 16x16. LDS: SMEM 128KB =
// A[buf][half] 4x16KB + B[buf][half] 4x16KB. K=1024 -> 16 tiles of BK=64.
__global__ __launch_bounds__(512) void gemm_xp(const unsigned short* __restrict__ A,
                                               const unsigned short* __restrict__ B,
                                               const float* __restrict__ bias,
                                               unsigned short* __restrict__ C) {
  __shared__ unsigned short SMEM[65536];  // 128 KB
  const int tid = threadIdx.x;
  const int lane = tid & 63;
  const int wid = tid >> 6;
  const int wm = wid >> 2;  // 0..1
  const int wn = wid & 3;   // 0..3
  const long brow = (long)blockIdx.x * 256;
  const long bcol = (long)blockIdx.y * 256;

  f32x4 acc[8][4];
  const f32x4 z = {0.f, 0.f, 0.f, 0.f};
#pragma unroll
  for (int m = 0; m < 8; ++m)
#pragma unroll
    for (int n = 0; n < 4; ++n) acc[m][n] = z;

  // staging geometry: 16KB half-slot, rows of 128B; inverse swizzle on source
  int srow[2], scol[2];
#pragma unroll
  for (int j = 0; j < 2; ++j) {
    const int o = (j * 512 + tid) * 16;
    srow[j] = o >> 7;                            // 0..127
    scol[j] = (o & 127) ^ ((srow[j] & 7) << 4);  // inverse swizzle
  }

#define STAGE_HALF(t, h, buf)                                                          \
  do {                                                                                 \
    const char* aA_ = (const char*)A + (brow + (h)*128) * 2048 + (t)*128;              \
    const char* aB_ = (const char*)B + (bcol + (h)*128) * 2048 + (t)*128;              \
    char* dA_ = (char*)(SMEM + ((buf)*2 + (h)) * 8192);                                \
    char* dB_ = (char*)(SMEM + 32768 + ((buf)*2 + (h)) * 8192);                        \
    _Pragma("unroll") for (int j_ = 0; j_ < 2; ++j_) {                                 \
      const int o_ = (j_ * 512 + tid) * 16;                                            \
      gl_lds16(aA_ + (long)srow[j_] * 2048 + scol[j_], dA_ + o_);                      \
      gl_lds16(aB_ + (long)srow[j_] * 2048 + scol[j_], dB_ + o_);                      \
    }                                                                                  \
  } while (0)

  // prologue: tile 0 both halves
  STAGE_HALF(0, 0, 0);
  STAGE_HALF(0, 1, 0);
  __syncthreads();

  const int p15 = lane & 15;
  const int kq = lane >> 4;  // 0..3

  for (int t = 0; t < 16; ++t) {
    const int cur = t & 1, nxt = cur ^ 1;
    const bool doStage = (t + 1 < 16);
    const unsigned short* Acur = SMEM + (cur * 2 + wm) * 8192;
    const unsigned short* Bcur = SMEM + 32768 + (cur * 2 + (wn >> 1)) * 8192;
#pragma unroll
    for (int p = 0; p < 4; ++p) {
      if (p < 2 && doStage) STAGE_HALF(t + 1, p, nxt);
      // ds_read fragments (proven swizzled layout)
      bf16x8 af[2][2], bf[4][2];
#pragma unroll
      for (int mm = 0; mm < 2; ++mm) {
        const int ar = (2 * p + mm) * 16 + p15;  // row in half, 0..127
        const char* abase = (const char*)Acur + ar * 128;
        const int asw = (ar & 7) << 4;
#pragma unroll
        for (int kk = 0; kk < 2; ++kk)
          af[mm][kk] = *(const bf16x8*)(abase + ((kk * 64 + kq * 16) ^ asw));
      }
#pragma unroll
      for (int n = 0; n < 4; ++n) {
        const int br = (wn & 1) * 64 + n * 16 + p15;  // row in half, 0..127
        const char* bbase = (const char*)Bcur + br * 128;
        const int bsw = (br & 7) << 4;
#pragma unroll
        for (int kk = 0; kk < 2; ++kk)
          bf[n][kk] = *(const bf16x8*)(bbase + ((kk * 64 + kq * 16) ^ bsw));
      }
      __builtin_amdgcn_s_barrier();
      __builtin_amdgcn_s_setprio(1);
#pragma unroll
      for (int kk = 0; kk < 2; ++kk)
#pragma unroll
        for (int mm = 0; mm < 2; ++mm)
#pragma unroll
          for (int n = 0; n < 4; ++n)
            acc[2 * p + mm][n] = __builtin_amdgcn_mfma_f32_16x16x32_bf16(
                af[mm][kk], bf[n][kk], acc[2 * p + mm][n], 0, 0, 0);
      __builtin_amdgcn_s_setprio(0);
      __builtin_amdgcn_s_barrier();
    }
    __syncthreads();  // tile boundary: drains staged t+1 loads (covered by 4 phases)
  }
#undef STAGE_HALF

  // epilogue: acc -> SMEM (bf16 + bias), then coalesced 16B stores
  const int crow0 = wm * 128 + kq * 4;
  const int ccol0 = wn * 64 + p15;
#pragma unroll
  for (int m = 0; m < 8; ++m) {
#pragma unroll
    for (int n = 0; n < 4; ++n) {
      const int col = ccol0 + n * 16;
      const float bsv = bias[bcol + col];
#pragma unroll
      for (int r = 0; r < 4; ++r)
        SMEM[(crow0 + m * 16 + r) * 256 + col] = f2bf(acc[m][n][r] + bsv);
    }
  }
  __syncthreads();
#pragma unroll
  for (int i = 0; i < 16; ++i) {
    const int id = i * 512 + tid;  // 8192 chunks of 16B
    const int row = id >> 5;       // 0..255
    const int c = id & 31;         // 16B chunk in row
    *(float4*)(C + (brow + row) * 4096 + bcol + c * 8) =
        *(const float4*)(SMEM + row * 256 + c * 8);
  }
}

// ---------------- persistent recurrence (r8-exact, 296us proven) ----------------
// 256 blocks x 256 thr. bid = ut*16 + grp; grp = dir*8 + cs.
// Block: 16 chains x 32 units x 4 gates, full K=512. W in REGISTERS
// (wreg[2][16] = 128 VGPR). Gate combine: shfl_xor(8).
// Out-stores for step tau issued at top of step tau+1; XP(tau+1) prefetched.
__global__ __launch_bounds__(256, 1) void lstm_persist(
    const unsigned short* __restrict__ XPb, const float* __restrict__ Whf,
    const float* __restrict__ Whb, unsigned short* __restrict__ hb0,
    unsigned short* __restrict__ hb1, float* __restrict__ out,
    unsigned int* __restrict__ ctr) {
  __shared__ unsigned short A_s[8192];     // 16 KB
  __shared__ unsigned short Hrep[16][32];  // 1 KB

  const int tid = threadIdx.x;
  const int bid = blockIdx.x;
  const int ut = bid >> 4;   // 0..15: 32-unit tile
  const int grp = bid & 15;  // group id
  const int dir = grp >> 3;
  const int cs = grp & 7;    // chain-set (16 chains) within dir
  const int lane = tid & 63;
  const int w = tid >> 6;    // wave id
  const int p = lane & 15;
  const int kq8 = lane >> 4;             // 0..3 k-chunk of B/A frag
  const int hi = p >> 3;                 // gate-pair half
  const int u_l = w * 8 + (p & 7);       // unit local 0..31
  const int u_g = ut * 32 + u_l;         // unit within dir 0..511
  unsigned int* const myctr = ctr + grp * 32;  // 128B stride

  // ---- W_hh slice -> registers (bf16 B-frags), once ----
  bf16x8 wreg[2][16];
  {
    const float* Wh = dir ? Whb : Whf;
#pragma unroll
    for (int f = 0; f < 2; ++f) {
      const int g = f * 2 + hi;
      const float* wrow = Wh + (size_t)(g * 512 + u_g) * 512 + kq8 * 8;
#pragma unroll
      for (int kk = 0; kk < 16; ++kk) {
        const float4 v0 = *(const float4*)(wrow + kk * 32);
        const float4 v1 = *(const float4*)(wrow + kk * 32 + 4);
        bf16x8 t;
        t[0] = (short)f2bf(v0.x); t[1] = (short)f2bf(v0.y);
        t[2] = (short)f2bf(v0.z); t[3] = (short)f2bf(v0.w);
        t[4] = (short)f2bf(v1.x); t[5] = (short)f2bf(v1.y);
        t[6] = (short)f2bf(v1.z); t[7] = (short)f2bf(v1.w);
        wreg[f][kk] = t;
      }
    }
  }

  float c_reg[2] = {0.f, 0.f};
  const size_t tileoff = (size_t)grp * 16384;  // bytes per group h tile (16 KB)
  const int cl0 = kq8 * 4 + 2 * hi;            // first of this lane's 2 chains

  // XP prefetch for tau=0
  unsigned short xpr[2][4];
  {
    const int tcol0 = dir ? 127 : 0;
#pragma unroll
    for (int j = 0; j < 2; ++j) {
      const int seg = cs * 16 + cl0 + j;
      const size_t tok = (size_t)seg * 128 + tcol0;
      const unsigned short* xp = XPb + tok * 4096 + dir * 2048 + u_g;
#pragma unroll
      for (int g = 0; g < 4; ++g) xpr[j][g] = xp[g * 512];
    }
  }

  float phv[2];
  size_t pofs[2] = {0, 0};

  for (int tau = 0; tau < 128; ++tau) {
    const unsigned short* hc = (tau & 1) ? hb1 : hb0;
    unsigned short* hn = (tau & 1) ? hb0 : hb1;
    const int tcol = dir ? (127 - tau) : tau;

    // stage h tile from LLC (pre-swizzled; linear 16 KB copy)
    {
      const char* srcb = (const char*)hc + tileoff;
      char* dstb = (char*)A_s;
#pragma unroll
      for (int j = 0; j < 4; ++j) {
        const int o = (j * 256 + tid) * 16;
        gl_lds16_llc(srcb + o, dstb + o);
      }
    }
    // deferred out-stores for previous step: drain overlaps the stage
    if (tau > 0) {
      out[pofs[0]] = phv[0];
      out[pofs[1]] = phv[1];
    }
    __syncthreads();  // A_s ready (drains stage + deferred out-stores)

    // XP prefetch for tau+1 (latency hidden under MFMA/gates)
    unsigned short xprN[2][4];
    if (tau < 127) {
      const int tcolN = dir ? (126 - tau) : (tau + 1);
#pragma unroll
      for (int j = 0; j < 2; ++j) {
        const int seg = cs * 16 + cl0 + j;
        const size_t tok = (size_t)seg * 128 + tcolN;
        const unsigned short* xp = XPb + tok * 4096 + dir * 2048 + u_g;
#pragma unroll
        for (int g = 0; g < 4; ++g) xprN[j][g] = xp[g * 512];
      }
    }

    // MFMA: full K=512; frag f=0 -> gates {0,1}, f=1 -> gates {2,3}
    f32x4 accp[2][2];
    const f32x4 z = {0.f, 0.f, 0.f, 0.f};
    accp[0][0] = z; accp[0][1] = z; accp[1][0] = z; accp[1][1] = z;
    {
      const char* abase = (const char*)A_s + p * 1024;  // A row = chain = p
      const int asw = (p & 7) << 4;
#pragma unroll
      for (int kk = 0; kk < 16; ++kk) {
        const int kb = kk * 64 + kq8 * 16;
        const bf16x8 af = *(const bf16x8*)(abase + (kb ^ asw));
        accp[0][kk & 1] =
            __builtin_amdgcn_mfma_f32_16x16x32_bf16(af, wreg[0][kk], accp[0][kk & 1], 0, 0, 0);
        accp[1][kk & 1] =
            __builtin_amdgcn_mfma_f32_16x16x32_bf16(af, wreg[1][kk], accp[1][kk & 1], 0, 0, 0);
      }
    }
    f32x4 acc0, acc1;
#pragma unroll
    for (int r = 0; r < 4; ++r) {
      acc0[r] = accp[0][0][r] + accp[0][1][r];
      acc1[r] = accp[1][0][r] + accp[1][1][r];
    }

    // gate combine: lane p (hi=0) holds gates {0,2}, lane p^8 holds {1,3}
    float hvr[2];
    {
      const float s0 = hi ? acc0[0] : acc0[2];
      const float s1 = hi ? acc0[1] : acc0[3];
      const float s2 = hi ? acc1[0] : acc1[2];
      const float s3 = hi ? acc1[1] : acc1[3];
      const float e0 = __shfl_xor(s0, 8);
      const float e1 = __shfl_xor(s1, 8);
      const float e2 = __shfl_xor(s2, 8);
      const float e3 = __shfl_xor(s3, 8);
      const float a0 = hi ? acc0[2] : acc0[0];
      const float a1 = hi ? acc0[3] : acc0[1];
      const float b0 = hi ? acc1[2] : acc1[0];
      const float b1 = hi ? acc1[3] : acc1[1];
      const float gi[2] = {hi ? e0 : a0, hi ? e1 : a1};
      const float gf[2] = {hi ? a0 : e0, hi ? a1 : e1};
      const float gg[2] = {hi ? e2 : b0, hi ? e3 : b1};
      const float go[2] = {hi ? b0 : e2, hi ? b1 : e3};
#pragma unroll
      for (int j = 0; j < 2; ++j) {
        const int cl = cl0 + j;
        const float pi = gi[j] + bf2f(xpr[j][0]);
        const float pf = gf[j] + bf2f(xpr[j][1]);
        const float pg = gg[j] + bf2f(xpr[j][2]);
        const float po = go[j] + bf2f(xpr[j][3]);
        float cv = sigm(pf) * c_reg[j] + sigm(pi) * tanhfast(pg);
        c_reg[j] = cv;
        hvr[j] = sigm(po) * tanhfast(cv);
        Hrep[cl][u_l] = f2bf(hvr[j]);
        const int seg = cs * 16 + cl;
        const size_t tok = (size_t)seg * 128 + tcol;
        pofs[j] = tok * 1024 + dir * 512 + u_g;
        phv[j] = hvr[j];
      }
    }
#pragma unroll
    for (int j = 0; j < 2; ++j)
#pragma unroll
      for (int g = 0; g < 4; ++g) xpr[j][g] = xprN[j][g];

    __syncthreads();  // Hrep complete

    // packed 8B LLC-coherent h stores (swizzled dest, 8B-block preserving)
    if (tid < 128) {
      const int cl = tid >> 3, q = tid & 7;
      const unsigned long long v = *(const unsigned long long*)&Hrep[cl][q * 4];
      char* dst = (char*)hn + tileoff + cl * 1024 + ((ut * 64 + q * 8) ^ ((cl & 7) << 4));
      __hip_atomic_store((unsigned long long*)dst, v, __ATOMIC_RELAXED,
                         __HIP_MEMORY_SCOPE_AGENT);
    }

    // ---- per-group barrier (fence-free, r4-r8 protocol) ----
    __syncthreads();  // drains vmcnt(0): sc1 stores are at LLC
    if (tid == 0) {
      const unsigned old =
          __hip_atomic_fetch_add(myctr, 1u, __ATOMIC_RELAXED, __HIP_MEMORY_SCOPE_AGENT);
      const unsigned tgt = (unsigned)(tau + 1) * 16u;
      if (old + 1u != tgt) {
        while (__hip_atomic_load(myctr, __ATOMIC_RELAXED, __HIP_MEMORY_SCOPE_AGENT) < tgt)
          __builtin_amdgcn_s_sleep(1);
      }
    }
    __syncthreads();
  }
  // flush final step's out-stores
  out[pofs[0]] = phv[0];
  out[pofs[1]] = phv[1];
}

// ---------------- boundaries passthrough ----------------
__global__ void wr_bounds(const int* __restrict__ b, float* __restrict__ o) {
  const int i = threadIdx.x;
  if (i < 129) o[i] = (float)b[i];
}

extern "C" void kernel_launch(void* const* d_in, const int* in_sizes, int n_in,
                              void* d_out, int out_size, void* d_ws, size_t ws_size,
                              hipStream_t stream) {
  const float* X = (const float*)d_in[0];
  const int* bnd = (const int*)d_in[1];
  const float* Wif = (const float*)d_in[2];
  const float* Whf = (const float*)d_in[3];
  const float* bf_ = (const float*)d_in[4];
  const float* Wib = (const float*)d_in[5];
  const float* Whb = (const float*)d_in[6];
  const float* bb_ = (const float*)d_in[7];
  float* out = (float*)d_out;

  wr_bounds<<<1, 256, 0, stream>>>(bnd, out + 16777216);

  char* ws = (char*)d_ws;
  const size_t NEED = 176703488ULL;
  if (ws_size < NEED) return;

  unsigned short* XPb = (unsigned short*)(ws + 0);          // 128 MB
  unsigned short* Xb = (unsigned short*)(ws + 134217728);   // 32 MB
  unsigned short* Wc = (unsigned short*)(ws + 167772160);   // 8 MB
  float* biasp = (float*)(ws + 176160768);                  // 16 KB
  unsigned short* hb0 = (unsigned short*)(ws + 176177152);  // 256 KB
  unsigned short* hb1 = (unsigned short*)(ws + 176439296);  // 256 KB
  unsigned int* ctrp = (unsigned int*)(ws + 176701440);     // 2 KB (16 x 128B)

  cast_x<<<16384, 256, 0, stream>>>(X, Xb);
  pack_w<<<4096, 256, 0, stream>>>(Wif, bf_, Wib, bb_, Wc, biasp);
  dim3 gg(64, 16);
  gemm_xp<<<gg, 512, 0, stream>>>(Xb, Wc, biasp, XPb);

  hipMemsetAsync(hb0, 0, 262144, stream);
  hipMemsetAsync(ctrp, 0, 2048, stream);

  {
    const unsigned short* xpb = XPb;
    const float* whf = Whf;
    const float* whb = Whb;
    unsigned short* h0 = hb0;
    unsigned short* h1 = hb1;
    float* op = out;
    unsigned int* cp = ctrp;
    void* args[] = {&xpb, &whf, &whb, &h0, &h1, &op, &cp};
    hipError_t e = hipLaunchCooperativeKernel((const void*)lstm_persist, dim3(256), dim3(256),
                                              args, 0, stream);
    if (e != hipSuccess) {
      lstm_persist<<<256, 256, 0, stream>>>(XPb, Whf, Whb, hb0, hb1, out, ctrp);
    }
  }
}